// Round 1
// baseline (951.768 us; speedup 1.0000x reference)
//
#include <hip/hip_runtime.h>
#include <cstdint>
#include <cstddef>

// SOM BMU search: dists[b,m] = ||x[b] - W[:,m] + eps||_2, argmin/min over m.
// Expansion (matches reference exactly):
//   sq = rowTerm[b] + colTerm[m] - 2*dot(x[b], W[:,m]) + D*eps^2
//   rowTerm[b] = sum_d (x^2 + 2 eps x)
//   colTerm[m] = sum_d (w^2 - 2 eps w)
// Argmin via packed u64 key (dist_bits<<32 | m): min-key == min dist,
// ties broken by smallest index (matches np.argmin first-occurrence).

#define B_  2048
#define D_  1024
#define M_  16384
#define EPS_ 1e-6f

static __device__ __forceinline__ unsigned long long umin64(unsigned long long a,
                                                            unsigned long long b) {
    return a < b ? a : b;
}

// ---------------- per-row stats of x ----------------
__global__ void row_stats(const float* __restrict__ x, float* __restrict__ rowTerm) {
    int b = blockIdx.x;
    const float* xr = x + (size_t)b * D_;
    int t = threadIdx.x;  // 256 threads
    float acc = 0.f;
    for (int i = t; i < D_; i += 256) {
        float v = xr[i];
        acc += v * v + 2.0f * EPS_ * v;
    }
    for (int off = 32; off; off >>= 1) acc += __shfl_down(acc, off, 64);
    __shared__ float s[4];
    if ((t & 63) == 0) s[t >> 6] = acc;
    __syncthreads();
    if (t == 0) rowTerm[b] = s[0] + s[1] + s[2] + s[3];
}

// ---------------- per-column stats of W ----------------
// grid (M/256, D/64); colTerm must be zeroed before launch.
__global__ void col_stats(const float* __restrict__ w, float* __restrict__ colTerm) {
    int m = blockIdx.x * 256 + threadIdx.x;
    int d0 = blockIdx.y * 64;
    const float* p = w + (size_t)d0 * M_ + m;
    float acc = 0.f;
    #pragma unroll 8
    for (int d = 0; d < 64; ++d) {
        float v = p[(size_t)d * M_];
        acc += v * v - 2.0f * EPS_ * v;
    }
    atomicAdd(&colTerm[m], acc);
}

// ---------------- fused distance GEMM + per-row argmin ----------------
// 128x128 tile per 256-thread block, BK=8, 8x8 micro-tile per thread.
__global__ __launch_bounds__(256, 2) void som_gemm(
    const float* __restrict__ A,    // x [B][D]
    const float* __restrict__ Wt,   // weight [D][M]
    const float* __restrict__ rowTerm,
    const float* __restrict__ colTerm,
    unsigned long long* __restrict__ keys)
{
    __shared__ float As[8][128];
    __shared__ float Bs[8][128];
    const int t  = threadIdx.x;
    const int rb = blockIdx.y * 128;
    const int cb = blockIdx.x * 128;
    const int tx = t & 15;
    const int ty = t >> 4;

    float acc[8][8];
    #pragma unroll
    for (int i = 0; i < 8; ++i)
        #pragma unroll
        for (int j = 0; j < 8; ++j) acc[i][j] = 0.f;

    // A load: thread -> (row = t>>1, k-quad = (t&1)*4)
    const int la_row = t >> 1, la_k = (t & 1) * 4;
    // B load: thread -> (k = t>>5, n = (t&31)*4); contiguous 512B per 32 lanes
    const int lb_k = t >> 5, lb_n = (t & 31) * 4;

    const float* Aptr = A + (size_t)(rb + la_row) * D_ + la_k;
    const float* Bptr = Wt + (size_t)lb_k * M_ + cb + lb_n;

    for (int k0 = 0; k0 < D_; k0 += 8) {
        float4 av = *(const float4*)(Aptr + k0);
        float4 bv = *(const float4*)(Bptr + (size_t)k0 * M_);
        __syncthreads();  // previous iteration's LDS reads done
        As[la_k + 0][la_row] = av.x;
        As[la_k + 1][la_row] = av.y;
        As[la_k + 2][la_row] = av.z;
        As[la_k + 3][la_row] = av.w;
        *(float4*)&Bs[lb_k][lb_n] = bv;
        __syncthreads();
        #pragma unroll
        for (int k = 0; k < 8; ++k) {
            float a[8], b[8];
            #pragma unroll
            for (int i = 0; i < 8; ++i) a[i] = As[k][ty * 8 + i];
            #pragma unroll
            for (int j = 0; j < 8; ++j) b[j] = Bs[k][tx * 8 + j];
            #pragma unroll
            for (int i = 0; i < 8; ++i)
                #pragma unroll
                for (int j = 0; j < 8; ++j) acc[i][j] += a[i] * b[j];
        }
    }

    // Epilogue: distances + per-row min/argmin
    float rT[8], cT[8];
    #pragma unroll
    for (int i = 0; i < 8; ++i) rT[i] = rowTerm[rb + ty * 8 + i];
    #pragma unroll
    for (int j = 0; j < 8; ++j) cT[j] = colTerm[cb + tx * 8 + j];
    const float de2 = (float)D_ * EPS_ * EPS_;

    #pragma unroll
    for (int i = 0; i < 8; ++i) {
        unsigned long long best = ~0ull;
        #pragma unroll
        for (int j = 0; j < 8; ++j) {
            float sq = rT[i] + cT[j] - 2.0f * acc[i][j] + de2;
            sq = fmaxf(sq, 0.0f);
            float dist = sqrtf(sq);
            unsigned long long key =
                ((unsigned long long)__float_as_uint(dist) << 32) |
                (unsigned int)(cb + tx * 8 + j);
            best = umin64(best, key);
        }
        // reduce across the 16 lanes sharing this row (tx = 0..15)
        #pragma unroll
        for (int msk = 1; msk <= 8; msk <<= 1) {
            unsigned long long o = __shfl_xor((long long)best, msk, 64);
            best = umin64(best, (unsigned long long)o);
        }
        if (tx == 0) atomicMin(&keys[rb + ty * 8 + i], best);
    }
}

// ---------------- finalize: indexes, locations, mean loss ----------------
__global__ void finalize(const unsigned long long* __restrict__ keys,
                         const float* __restrict__ loc,
                         float* __restrict__ out)
{
    int t = threadIdx.x;  // 256
    float sum = 0.f;
    for (int r = t; r < B_; r += 256) {
        unsigned long long k = keys[r];
        unsigned int idx = (unsigned int)(k & 0xFFFFFFFFu);
        float dist = __uint_as_float((unsigned int)(k >> 32));
        out[r] = (float)idx;
        out[B_ + 2 * r]     = loc[2 * idx];
        out[B_ + 2 * r + 1] = loc[2 * idx + 1];
        sum += dist;
    }
    for (int off = 32; off; off >>= 1) sum += __shfl_down(sum, off, 64);
    __shared__ float s[4];
    if ((t & 63) == 0) s[t >> 6] = sum;
    __syncthreads();
    if (t == 0) out[3 * B_] = (s[0] + s[1] + s[2] + s[3]) / (float)B_;
}

extern "C" void kernel_launch(void* const* d_in, const int* in_sizes, int n_in,
                              void* d_out, int out_size, void* d_ws, size_t ws_size,
                              hipStream_t stream)
{
    const float* x   = (const float*)d_in[0];
    const float* w   = (const float*)d_in[1];
    const float* loc = (const float*)d_in[2];
    float* out = (float*)d_out;

    char* ws = (char*)d_ws;
    unsigned long long* keys = (unsigned long long*)ws;            // 16 KB
    float* rowTerm = (float*)(ws + 16 * 1024);                     //  8 KB
    float* colTerm = (float*)(ws + 24 * 1024);                     // 64 KB

    hipMemsetAsync(keys, 0xFF, B_ * sizeof(unsigned long long), stream);
    hipMemsetAsync(colTerm, 0, M_ * sizeof(float), stream);

    row_stats<<<B_, 256, 0, stream>>>(x, rowTerm);
    col_stats<<<dim3(M_ / 256, D_ / 64), 256, 0, stream>>>(w, colTerm);
    som_gemm<<<dim3(M_ / 128, B_ / 128), 256, 0, stream>>>(x, w, rowTerm, colTerm, keys);
    finalize<<<1, 256, 0, stream>>>(keys, loc, out);
}

// Round 2
// 356.331 us; speedup vs baseline: 2.6710x; 2.6710x over previous
//
#include <hip/hip_runtime.h>
#include <cstdint>
#include <cstddef>

// SOM BMU: dists[b,m] = ||x[b] - W[:,m] + eps||, argmin/min over m.
//   sq = rowTerm[b] + colTerm[m] - 2*dot(x[b],W[:,m]) + D*eps^2
// dot computed via split-precision f16 MFMA: x=xh+xl, w=wh+wl,
// dot ~= xh.wh + xh.wl + xl.wh  (lo*lo dropped, ~2^-22 rel err).
// Argmin via packed u64 key (dist_bits<<32 | m) + atomicMin.

#define B_  2048
#define D_  1024
#define M_  16384
#define EPS_ 1e-6f

typedef _Float16 v8h __attribute__((ext_vector_type(8)));
typedef _Float16 v4h __attribute__((ext_vector_type(4)));
typedef float    v4f __attribute__((ext_vector_type(4)));

static __device__ __forceinline__ unsigned long long umin64(unsigned long long a,
                                                            unsigned long long b) {
    return a < b ? a : b;
}

#define GLDS16(g, l)                                                            \
    __builtin_amdgcn_global_load_lds(                                           \
        (const __attribute__((address_space(1))) void*)(g),                     \
        (__attribute__((address_space(3))) void*)(l), 16, 0, 0)

// ---------- convert x -> xh,xl (f16) + rowTerm ----------
__global__ void xconv(const float* __restrict__ x,
                      _Float16* __restrict__ xh, _Float16* __restrict__ xl,
                      float* __restrict__ rowTerm) {
    int b = blockIdx.x;
    int t = threadIdx.x;  // 256
    const float4 v = *(const float4*)(x + (size_t)b * D_ + t * 4);
    v4h h, l;
    float acc = 0.f;
    float vv[4] = {v.x, v.y, v.z, v.w};
    #pragma unroll
    for (int e = 0; e < 4; ++e) {
        _Float16 hi = (_Float16)vv[e];
        float lo = vv[e] - (float)hi;
        h[e] = hi; l[e] = (_Float16)lo;
        acc += vv[e] * vv[e] + 2.0f * EPS_ * vv[e];
    }
    *(v4h*)(xh + (size_t)b * D_ + t * 4) = h;
    *(v4h*)(xl + (size_t)b * D_ + t * 4) = l;
    for (int off = 32; off; off >>= 1) acc += __shfl_down(acc, off, 64);
    __shared__ float s[4];
    if ((t & 63) == 0) s[t >> 6] = acc;
    __syncthreads();
    if (t == 0) rowTerm[b] = s[0] + s[1] + s[2] + s[3];
}

// ---------- convert+transpose W -> Wth,Wtl [m][d] + colTerm ----------
// grid (M/64, D/64), 256 threads. colTerm must be zeroed first.
__global__ void wconv(const float* __restrict__ W,
                      _Float16* __restrict__ wth, _Float16* __restrict__ wtl,
                      float* __restrict__ colTerm) {
    __shared__ float tile[64][65];
    const int t = threadIdx.x;
    const int m0 = blockIdx.x * 64;
    const int d0 = blockIdx.y * 64;
    const int dloc = t >> 4, mq = (t & 15) * 4;
    #pragma unroll
    for (int s = 0; s < 4; ++s) {
        float4 v = *(const float4*)(W + (size_t)(d0 + dloc + 16 * s) * M_ + m0 + mq);
        tile[dloc + 16 * s][mq + 0] = v.x;
        tile[dloc + 16 * s][mq + 1] = v.y;
        tile[dloc + 16 * s][mq + 2] = v.z;
        tile[dloc + 16 * s][mq + 3] = v.w;
    }
    __syncthreads();
    const int dc = (t & 7) * 8;
    #pragma unroll
    for (int p = 0; p < 2; ++p) {
        int mloc = (t >> 3) + 32 * p;
        v8h h, l;
        float acc = 0.f;
        #pragma unroll
        for (int e = 0; e < 8; ++e) {
            float v = tile[dc + e][mloc];
            _Float16 hi = (_Float16)v;
            float lo = v - (float)hi;
            h[e] = hi; l[e] = (_Float16)lo;
            acc += v * v - 2.0f * EPS_ * v;
        }
        *(v8h*)(wth + (size_t)(m0 + mloc) * D_ + d0 + dc) = h;
        *(v8h*)(wtl + (size_t)(m0 + mloc) * D_ + d0 + dc) = l;
        acc += __shfl_down(acc, 4, 8);
        acc += __shfl_down(acc, 2, 8);
        acc += __shfl_down(acc, 1, 8);
        if ((t & 7) == 0) atomicAdd(&colTerm[m0 + mloc], acc);
    }
}

// ---------- main MFMA distance GEMM + argmin ----------
// 128x128 tile, 4 waves (2x2 of 64x64), BK=32, 16x16x32 f16 MFMA.
__global__ __launch_bounds__(256, 2) void som_mfma(
    const _Float16* __restrict__ xh, const _Float16* __restrict__ xl,
    const _Float16* __restrict__ wth, const _Float16* __restrict__ wtl,
    const float* __restrict__ rowTerm, const float* __restrict__ colTerm,
    unsigned long long* __restrict__ keys)
{
    __shared__ __align__(16) _Float16 smem[16384];  // 32 KB: Ah|Al|Bh|Bl
    _Float16* Ah = smem;
    _Float16* Al = smem + 4096;
    _Float16* Bh = smem + 8192;
    _Float16* Bl = smem + 12288;

    const int t  = threadIdx.x;
    const int rb = blockIdx.y * 128;
    const int cb = blockIdx.x * 128;
    const int L  = t & 63, w = t >> 6;
    const int wro = (w >> 1) * 64, wco = (w & 1) * 64;
    const int c16 = L & 15, kq = L >> 4;

    // staging: element u covers LDS bytes [u*16, u*16+16) = row u>>2, k-chunk u&3
    const int u1 = t, u2 = t + 256;
    const size_t aoff1 = (size_t)(rb + (u1 >> 2)) * 2048 + (u1 & 3) * 16;
    const size_t aoff2 = (size_t)(rb + (u2 >> 2)) * 2048 + (u2 & 3) * 16;
    const size_t boff1 = (size_t)(cb + (u1 >> 2)) * 2048 + (u1 & 3) * 16;
    const size_t boff2 = (size_t)(cb + (u2 >> 2)) * 2048 + (u2 & 3) * 16;
    const int lds1 = (t & 192) * 16;          // wave-uniform base, chunk 0
    const int lds2 = (256 + (t & 192)) * 16;  // chunk 1
    const char* pxh = (const char*)xh;
    const char* pxl = (const char*)xl;
    const char* pwh = (const char*)wth;
    const char* pwl = (const char*)wtl;

    v4f acc[4][4];
    #pragma unroll
    for (int i = 0; i < 4; ++i)
        #pragma unroll
        for (int j = 0; j < 4; ++j) acc[i][j] = (v4f){0.f, 0.f, 0.f, 0.f};

    for (int kb = 0; kb < 2048; kb += 64) {  // 2048 bytes per row; 64 B = BK(32 f16)
        __syncthreads();
        GLDS16(pxh + aoff1 + kb, (char*)Ah + lds1);
        GLDS16(pxh + aoff2 + kb, (char*)Ah + lds2);
        GLDS16(pxl + aoff1 + kb, (char*)Al + lds1);
        GLDS16(pxl + aoff2 + kb, (char*)Al + lds2);
        GLDS16(pwh + boff1 + kb, (char*)Bh + lds1);
        GLDS16(pwh + boff2 + kb, (char*)Bh + lds2);
        GLDS16(pwl + boff1 + kb, (char*)Bl + lds1);
        GLDS16(pwl + boff2 + kb, (char*)Bl + lds2);
        __syncthreads();

        v8h ah[4], al4[4], bh[4], bl4[4];
        #pragma unroll
        for (int i = 0; i < 4; ++i) {
            int ra = (wro + i * 16 + c16) * 32 + kq * 8;
            int rbx = (wco + i * 16 + c16) * 32 + kq * 8;
            ah[i]  = *(const v8h*)(Ah + ra);
            al4[i] = *(const v8h*)(Al + ra);
            bh[i]  = *(const v8h*)(Bh + rbx);
            bl4[i] = *(const v8h*)(Bl + rbx);
        }
        #pragma unroll
        for (int i = 0; i < 4; ++i)
            #pragma unroll
            for (int j = 0; j < 4; ++j) {
                acc[i][j] = __builtin_amdgcn_mfma_f32_16x16x32_f16(ah[i],  bh[j],  acc[i][j], 0, 0, 0);
                acc[i][j] = __builtin_amdgcn_mfma_f32_16x16x32_f16(ah[i],  bl4[j], acc[i][j], 0, 0, 0);
                acc[i][j] = __builtin_amdgcn_mfma_f32_16x16x32_f16(al4[i], bh[j],  acc[i][j], 0, 0, 0);
            }
    }

    // epilogue: C/D layout col=lane&15, row=(lane>>4)*4+reg  [verified m89/m91]
    float cT[4];
    #pragma unroll
    for (int j = 0; j < 4; ++j) cT[j] = colTerm[cb + wco + j * 16 + c16];
    const float de2 = (float)D_ * EPS_ * EPS_;
    #pragma unroll
    for (int i = 0; i < 4; ++i) {
        #pragma unroll
        for (int r = 0; r < 4; ++r) {
            int row_g = rb + wro + i * 16 + kq * 4 + r;
            float rt = rowTerm[row_g];
            unsigned long long best = ~0ull;
            #pragma unroll
            for (int j = 0; j < 4; ++j) {
                float sq = rt + cT[j] - 2.0f * acc[i][j][r] + de2;
                sq = fmaxf(sq, 0.0f);
                float dist = sqrtf(sq);
                unsigned long long key =
                    ((unsigned long long)__float_as_uint(dist) << 32) |
                    (unsigned int)(cb + wco + j * 16 + c16);
                best = umin64(best, key);
            }
            #pragma unroll
            for (int m = 1; m <= 8; m <<= 1) {
                unsigned long long o =
                    (unsigned long long)__shfl_xor((long long)best, m, 64);
                best = umin64(best, o);
            }
            if (c16 == 0) atomicMin(&keys[row_g], best);
        }
    }
}

// ---------- fallback fp32 path (used only if ws too small) ----------
__global__ void row_stats(const float* __restrict__ x, float* __restrict__ rowTerm) {
    int b = blockIdx.x;
    const float* xr = x + (size_t)b * D_;
    int t = threadIdx.x;
    float acc = 0.f;
    for (int i = t; i < D_; i += 256) {
        float v = xr[i];
        acc += v * v + 2.0f * EPS_ * v;
    }
    for (int off = 32; off; off >>= 1) acc += __shfl_down(acc, off, 64);
    __shared__ float s[4];
    if ((t & 63) == 0) s[t >> 6] = acc;
    __syncthreads();
    if (t == 0) rowTerm[b] = s[0] + s[1] + s[2] + s[3];
}

__global__ void col_stats(const float* __restrict__ w, float* __restrict__ colTerm) {
    int m = blockIdx.x * 256 + threadIdx.x;
    int d0 = blockIdx.y * 64;
    const float* p = w + (size_t)d0 * M_ + m;
    float acc = 0.f;
    #pragma unroll 8
    for (int d = 0; d < 64; ++d) {
        float v = p[(size_t)d * M_];
        acc += v * v - 2.0f * EPS_ * v;
    }
    atomicAdd(&colTerm[m], acc);
}

__global__ __launch_bounds__(256, 2) void som_gemm(
    const float* __restrict__ A, const float* __restrict__ Wt,
    const float* __restrict__ rowTerm, const float* __restrict__ colTerm,
    unsigned long long* __restrict__ keys)
{
    __shared__ float As[8][128];
    __shared__ float Bs[8][128];
    const int t  = threadIdx.x;
    const int rb = blockIdx.y * 128;
    const int cb = blockIdx.x * 128;
    const int tx = t & 15;
    const int ty = t >> 4;
    float acc[8][8];
    #pragma unroll
    for (int i = 0; i < 8; ++i)
        #pragma unroll
        for (int j = 0; j < 8; ++j) acc[i][j] = 0.f;
    const int la_row = t >> 1, la_k = (t & 1) * 4;
    const int lb_k = t >> 5, lb_n = (t & 31) * 4;
    const float* Aptr = A + (size_t)(rb + la_row) * D_ + la_k;
    const float* Bptr = Wt + (size_t)lb_k * M_ + cb + lb_n;
    for (int k0 = 0; k0 < D_; k0 += 8) {
        float4 av = *(const float4*)(Aptr + k0);
        float4 bv = *(const float4*)(Bptr + (size_t)k0 * M_);
        __syncthreads();
        As[la_k + 0][la_row] = av.x;
        As[la_k + 1][la_row] = av.y;
        As[la_k + 2][la_row] = av.z;
        As[la_k + 3][la_row] = av.w;
        *(float4*)&Bs[lb_k][lb_n] = bv;
        __syncthreads();
        #pragma unroll
        for (int k = 0; k < 8; ++k) {
            float a[8], b[8];
            #pragma unroll
            for (int i = 0; i < 8; ++i) a[i] = As[k][ty * 8 + i];
            #pragma unroll
            for (int j = 0; j < 8; ++j) b[j] = Bs[k][tx * 8 + j];
            #pragma unroll
            for (int i = 0; i < 8; ++i)
                #pragma unroll
                for (int j = 0; j < 8; ++j) acc[i][j] += a[i] * b[j];
        }
    }
    float rT[8], cT[8];
    #pragma unroll
    for (int i = 0; i < 8; ++i) rT[i] = rowTerm[rb + ty * 8 + i];
    #pragma unroll
    for (int j = 0; j < 8; ++j) cT[j] = colTerm[cb + tx * 8 + j];
    const float de2 = (float)D_ * EPS_ * EPS_;
    #pragma unroll
    for (int i = 0; i < 8; ++i) {
        unsigned long long best = ~0ull;
        #pragma unroll
        for (int j = 0; j < 8; ++j) {
            float sq = rT[i] + cT[j] - 2.0f * acc[i][j] + de2;
            sq = fmaxf(sq, 0.0f);
            float dist = sqrtf(sq);
            unsigned long long key =
                ((unsigned long long)__float_as_uint(dist) << 32) |
                (unsigned int)(cb + tx * 8 + j);
            best = umin64(best, key);
        }
        #pragma unroll
        for (int msk = 1; msk <= 8; msk <<= 1) {
            unsigned long long o = __shfl_xor((long long)best, msk, 64);
            best = umin64(best, (unsigned long long)o);
        }
        if (tx == 0) atomicMin(&keys[rb + ty * 8 + i], best);
    }
}

// ---------- finalize ----------
__global__ void finalize(const unsigned long long* __restrict__ keys,
                         const float* __restrict__ loc,
                         float* __restrict__ out)
{
    int t = threadIdx.x;
    float sum = 0.f;
    for (int r = t; r < B_; r += 256) {
        unsigned long long k = keys[r];
        unsigned int idx = (unsigned int)(k & 0xFFFFFFFFu);
        float dist = __uint_as_float((unsigned int)(k >> 32));
        out[r] = (float)idx;
        out[B_ + 2 * r]     = loc[2 * idx];
        out[B_ + 2 * r + 1] = loc[2 * idx + 1];
        sum += dist;
    }
    for (int off = 32; off; off >>= 1) sum += __shfl_down(sum, off, 64);
    __shared__ float s[4];
    if ((t & 63) == 0) s[t >> 6] = sum;
    __syncthreads();
    if (t == 0) out[3 * B_] = (s[0] + s[1] + s[2] + s[3]) / (float)B_;
}

extern "C" void kernel_launch(void* const* d_in, const int* in_sizes, int n_in,
                              void* d_out, int out_size, void* d_ws, size_t ws_size,
                              hipStream_t stream)
{
    const float* x   = (const float*)d_in[0];
    const float* w   = (const float*)d_in[1];
    const float* loc = (const float*)d_in[2];
    float* out = (float*)d_out;

    char* ws = (char*)d_ws;
    unsigned long long* keys = (unsigned long long*)ws;   // 16 KB
    float* rowTerm = (float*)(ws + (16 << 10));           //  8 KB
    float* colTerm = (float*)(ws + (24 << 10));           // 64 KB
    _Float16* xh  = (_Float16*)(ws + (1ull << 20));       //  4 MB
    _Float16* xl  = (_Float16*)(ws + (5ull << 20));       //  4 MB
    _Float16* wth = (_Float16*)(ws + (9ull << 20));       // 32 MB
    _Float16* wtl = (_Float16*)(ws + (41ull << 20));      // 32 MB
    const size_t NEED = 73ull << 20;

    hipMemsetAsync(keys, 0xFF, B_ * sizeof(unsigned long long), stream);
    hipMemsetAsync(colTerm, 0, M_ * sizeof(float), stream);

    if (ws_size >= NEED) {
        xconv<<<B_, 256, 0, stream>>>(x, xh, xl, rowTerm);
        wconv<<<dim3(M_ / 64, D_ / 64), 256, 0, stream>>>(w, wth, wtl, colTerm);
        som_mfma<<<dim3(M_ / 128, B_ / 128), 256, 0, stream>>>(
            xh, xl, wth, wtl, rowTerm, colTerm, keys);
    } else {
        row_stats<<<B_, 256, 0, stream>>>(x, rowTerm);
        col_stats<<<dim3(M_ / 256, D_ / 64), 256, 0, stream>>>(w, colTerm);
        som_gemm<<<dim3(M_ / 128, B_ / 128), 256, 0, stream>>>(
            x, w, rowTerm, colTerm, keys);
    }
    finalize<<<1, 256, 0, stream>>>(keys, loc, out);
}